// Round 1
// baseline (222.858 us; speedup 1.0000x reference)
//
#include <hip/hip_runtime.h>
#include <hip/hip_bf16.h>

#define NQ 12
#define DIM 4096          // 2^12
#define BLK 256
#define NLAYER 2

// qubit i lives at bit (11 - i) of the flat amplitude index (axis 1 of the
// reshape is the most-significant bit).

__global__ __launch_bounds__(BLK, 4)
void qsim_kernel(const float* __restrict__ sv,      // [B, 4096] fp32 (real init states)
                 const float* __restrict__ angles,  // [96]
                 const float* __restrict__ W,       // [10, 36]
                 const float* __restrict__ bvec,    // [10]
                 float* __restrict__ out)           // [B, 10]
{
    __shared__ float2 psi[DIM];            // 32 KB state
    __shared__ float  gU[NLAYER][NQ][8];   // fused Rz*Ry*Rx 2x2 complex per (layer,qubit)
    __shared__ float  gC[NLAYER][NQ][2];   // CRX (cos, sin) half-angle per (layer,ring-slot)
    __shared__ float  red[36][4];          // cross-wave reduction
    __shared__ float  feats[36];

    const int tid = threadIdx.x;
    const int b   = blockIdx.x;

    // ---- per-block gate-parameter setup (redundant per block; trivial cost) ----
    if (tid < 24) {
        int l = tid / NQ, i = tid % NQ;
        float tx = angles[48*l + i];
        float ty = angles[48*l + 12 + i];
        float tz = angles[48*l + 24 + i];
        float cx = cosf(0.5f*tx), sx = sinf(0.5f*tx);
        float cy = cosf(0.5f*ty), sy = sinf(0.5f*ty);
        float cz = cosf(0.5f*tz), sz = sinf(0.5f*tz);
        // A = Ry*Rx
        float A00r = cy*cx, A00i =  sy*sx;
        float A01r = -sy*cx, A01i = -cy*sx;
        float A10r =  sy*cx, A10i = -cy*sx;
        float A11r =  cy*cx, A11i = -sy*sx;
        // U = Rz*A ; row0 *= e^{-i tz/2} = (cz,-sz), row1 *= (cz,+sz)
        float* u = gU[l][i];
        u[0] = cz*A00r + sz*A00i;  u[1] = cz*A00i - sz*A00r;
        u[2] = cz*A01r + sz*A01i;  u[3] = cz*A01i - sz*A01r;
        u[4] = cz*A10r - sz*A10i;  u[5] = cz*A10i + sz*A10r;
        u[6] = cz*A11r - sz*A11i;  u[7] = cz*A11i + sz*A11r;
    } else if (tid < 48) {
        int t2 = tid - 24;
        int l = t2 / NQ, g = t2 % NQ;
        float th = angles[48*l + 36 + g];
        gC[l][g][0] = cosf(0.5f*th);
        gC[l][g][1] = sinf(0.5f*th);
    }

    // ---- load state: coalesced global read, stride-1 LDS write (conflict-free) ----
    const float* svb = sv + (size_t)b * DIM;
#pragma unroll
    for (int j = 0; j < DIM/BLK; ++j) {
        int e = tid + j*BLK;
        psi[e] = make_float2(svb[e], 0.0f);
    }

    // ---- gate sweeps ----
    for (int l = 0; l < NLAYER; ++l) {
        // fused 1-qubit gates (commute; order within layer irrelevant)
        for (int i = 0; i < NQ; ++i) {
            __syncthreads();
            const float* u = gU[l][i];
            float u00r=u[0], u00i=u[1], u01r=u[2], u01i=u[3];
            float u10r=u[4], u10i=u[5], u11r=u[6], u11i=u[7];
            const int k = 11 - i;
            const int mlo = (1 << k) - 1;
#pragma unroll
            for (int j = 0; j < (DIM/2)/BLK; ++j) {
                int p  = tid + j*BLK;                      // 0..2047
                int i0 = ((p & ~mlo) << 1) | (p & mlo);    // insert 0 at bit k
                int i1 = i0 | (1 << k);
                float2 a0 = psi[i0], a1 = psi[i1];
                float2 n0, n1;
                n0.x = u00r*a0.x - u00i*a0.y + u01r*a1.x - u01i*a1.y;
                n0.y = u00r*a0.y + u00i*a0.x + u01r*a1.y + u01i*a1.x;
                n1.x = u10r*a0.x - u10i*a0.y + u11r*a1.x - u11i*a1.y;
                n1.y = u10r*a0.y + u10i*a0.x + u11r*a1.y + u11i*a1.x;
                psi[i0] = n0; psi[i1] = n1;
            }
        }
        // CRX ring (sequential; shared wires)
        for (int g = 0; g < NQ; ++g) {
            __syncthreads();
            int ctrl = (l == 0) ? g : 11 - g;
            int tgt  = (ctrl == 11) ? 0 : ctrl + 1;
            float c = gC[l][g][0], s = gC[l][g][1];
            int bc = 11 - ctrl, bt = 11 - tgt;
            int blo = bc < bt ? bc : bt;
            int bhi = bc < bt ? bt : bc;
            int mloB = (1 << blo) - 1;
            int mhiB = (1 << bhi) - 1;
#pragma unroll
            for (int j = 0; j < (DIM/4)/BLK; ++j) {
                int p  = tid + j*BLK;                        // 0..1023
                int t1 = ((p  & ~mloB) << 1) | (p  & mloB);  // insert 0 at blo
                int t2 = ((t1 & ~mhiB) << 1) | (t1 & mhiB);  // insert 0 at bhi
                int i0 = t2 | (1 << bc);                     // control = 1
                int i1 = i0 | (1 << bt);                     // target 0 / 1 pair
                float2 a0 = psi[i0], a1 = psi[i1];
                // RX on target: a0' = c*a0 - i s*a1 ; a1' = -i s*a0 + c*a1
                float2 n0, n1;
                n0.x =  c*a0.x + s*a1.y;
                n0.y =  c*a0.y - s*a1.x;
                n1.x =  s*a0.y + c*a1.x;
                n1.y = -s*a0.x + c*a1.y;
                psi[i0] = n0; psi[i1] = n1;
            }
        }
    }

    // ---- expectation values ----
    __syncthreads();
    float ax[NQ], ay[NQ], az[NQ];
#pragma unroll
    for (int i = 0; i < NQ; ++i) { ax[i] = 0.f; ay[i] = 0.f; az[i] = 0.f; }

#pragma unroll
    for (int i = 0; i < NQ; ++i) {
        const int k = 11 - i;
        const int mlo = (1 << k) - 1;
#pragma unroll
        for (int j = 0; j < (DIM/2)/BLK; ++j) {
            int p  = tid + j*BLK;
            int i0 = ((p & ~mlo) << 1) | (p & mlo);
            int i1 = i0 | (1 << k);
            float2 a0 = psi[i0], a1 = psi[i1];
            az[i] += a0.x*a0.x + a0.y*a0.y - a1.x*a1.x - a1.y*a1.y;
            ax[i] += a0.x*a1.x + a0.y*a1.y;   // Re(conj(a0)*a1)
            ay[i] += a0.x*a1.y - a0.y*a1.x;   // Im(conj(a0)*a1)
        }
    }

    // wave64 butterfly reduce, then cross-wave via LDS
#pragma unroll
    for (int i = 0; i < NQ; ++i) {
#pragma unroll
        for (int off = 32; off > 0; off >>= 1) {
            ax[i] += __shfl_xor(ax[i], off);
            ay[i] += __shfl_xor(ay[i], off);
            az[i] += __shfl_xor(az[i], off);
        }
    }
    int lane = tid & 63, w = tid >> 6;
    if (lane == 0) {
#pragma unroll
        for (int i = 0; i < NQ; ++i) {
            red[i][w]      = 2.0f * ax[i];
            red[12 + i][w] = 2.0f * ay[i];
            red[24 + i][w] = az[i];
        }
    }
    __syncthreads();
    if (tid < 36) feats[tid] = red[tid][0] + red[tid][1] + red[tid][2] + red[tid][3];
    __syncthreads();

    // ---- linear head: out[b,c] = feats . W[c,:] + b[c] ----
    if (tid < 10) {
        float acc = bvec[tid];
        const float* wrow = W + tid * 36;
#pragma unroll
        for (int f = 0; f < 36; ++f) acc += feats[f] * wrow[f];
        out[(size_t)b * 10 + tid] = acc;
    }
}

extern "C" void kernel_launch(void* const* d_in, const int* in_sizes, int n_in,
                              void* d_out, int out_size, void* d_ws, size_t ws_size,
                              hipStream_t stream) {
    const float* sv     = (const float*)d_in[0];
    const float* angles = (const float*)d_in[1];
    const float* W      = (const float*)d_in[2];
    const float* bvec   = (const float*)d_in[3];
    float* out = (float*)d_out;
    int batch = in_sizes[0] / DIM;   // 2048
    qsim_kernel<<<batch, BLK, 0, stream>>>(sv, angles, W, bvec, out);
}